// Round 1
// baseline (17.923 us; speedup 1.0000x reference)
//
#include <hip/hip_runtime.h>

#define P 1024
#define C 8
#define D 8
#define K 8

// out[n,d,b] = sum_{k,c} W[d,c,k] * T[k,c],  T[k,c] = sum_a exp(-8(r-ck)^2)*mask*input[c,a]
__global__ __launch_bounds__(256, 2) void se3_conv_kernel(
    const float* __restrict__ input,   // [n, C, P]
    const float* __restrict__ diff,    // [n, P, P, 3]
    const float* __restrict__ mask,    // [n, P, P]
    const float* __restrict__ W,       // [D, C, K]
    float* __restrict__ out)           // [n, D, P]
{
    const int b    = blockIdx.x;
    const int n    = blockIdx.y;
    const int tid  = threadIdx.x;
    const int lane = tid & 63;
    const int wave = tid >> 6;

    const float* diff_row = diff + (((size_t)n * P + b) * P) * 3;
    const float* mask_row = mask + ((size_t)n * P + b) * P;
    const float* inp_n    = input + (size_t)n * C * P;

    float acc[K * C];
    #pragma unroll
    for (int i = 0; i < K * C; ++i) acc[i] = 0.0f;

    const float step = 2.0f / 7.0f;   // linspace(0, 2, 8) spacing
    // basis_k(r) = exp(-(r - k*step)^2 / (2*0.25^2)) = exp(-8*(r-ck)^2)

    #pragma unroll
    for (int j = 0; j < 4; ++j) {
        const int a = tid + j * 256;
        const float x = diff_row[a * 3 + 0];
        const float y = diff_row[a * 3 + 1];
        const float z = diff_row[a * 3 + 2];
        const float m = mask_row[a];
        const float r = sqrtf(x * x + y * y + z * z);

        float basis[K];
        #pragma unroll
        for (int k = 0; k < K; ++k) {
            const float t = r - step * (float)k;
            basis[k] = __expf(-8.0f * t * t) * m;
        }

        float inp[C];
        #pragma unroll
        for (int c = 0; c < C; ++c) inp[c] = inp_n[c * P + a];

        #pragma unroll
        for (int k = 0; k < K; ++k)
            #pragma unroll
            for (int c = 0; c < C; ++c)
                acc[k * C + c] += basis[k] * inp[c];
    }

    // -------- wave-level reduce-scatter (recursive halving) --------
    // After 6 steps, lane l holds sum over the wave of acc[bitrev6(l)].
    #pragma unroll
    for (int s = 0; s < 6; ++s) {
        const int half = 32 >> s;
        const int bit  = (lane >> s) & 1;
        #pragma unroll
        for (int i = 0; i < half; ++i) {
            const float send = bit ? acc[i] : acc[i + half];
            const float recv = __shfl_xor(send, 1 << s, 64);
            const float keep = bit ? acc[i + half] : acc[i];
            acc[i] = keep + recv;
        }
    }

    __shared__ float red[4][64];
    __shared__ float ttot[64];

    const int j64 = (int)(__brev((unsigned)lane) >> 26);  // bitrev6(lane)
    red[wave][j64] = acc[0];
    __syncthreads();

    if (tid < 64) {
        ttot[tid] = red[0][tid] + red[1][tid] + red[2][tid] + red[3][tid];
    }
    __syncthreads();

    if (tid < D) {
        const int d = tid;
        float o = 0.0f;
        #pragma unroll
        for (int i = 0; i < 64; ++i) {
            const int k = i >> 3;
            const int c = i & 7;
            o += W[(d * C + c) * K + k] * ttot[i];
        }
        out[((size_t)n * D + d) * P + b] = o;
    }
}

extern "C" void kernel_launch(void* const* d_in, const int* in_sizes, int n_in,
                              void* d_out, int out_size, void* d_ws, size_t ws_size,
                              hipStream_t stream) {
    const float* input = (const float*)d_in[0];   // [2, 8, 1024]
    const float* diff  = (const float*)d_in[1];   // [2, 1024, 1024, 3]
    const float* mask  = (const float*)d_in[2];   // [2, 1024, 1024]
    const float* W     = (const float*)d_in[3];   // [8, 8, 8]
    float* out = (float*)d_out;                   // [2, 8, 1024]

    dim3 grid(P, 2);
    se3_conv_kernel<<<grid, 256, 0, stream>>>(input, diff, mask, W, out);
}